// Round 2
// baseline (2247.842 us; speedup 1.0000x reference)
//
#include <hip/hip_runtime.h>
#include <math.h>

#define B_ 8
#define T_ 12
#define N_ 500
#define D_ 64
#define K_ 20
#define M_ (B_*T_)              // 96
#define MND_ 3072000            // M_*N_*D_
#define NROWS_ 48000            // M_*N_

// workspace layout (float offsets)
#define XS_OFF  0ul                     // 3 stages x 2 mix x MND_
#define AGG_OFF (6ul*MND_)              // 4 x MND_
#define WC_OFF  (AGG_OFF + 4ul*MND_)    // 8*2*4096
#define WD_OFF  (WC_OFF + 65536ul)
#define BC_OFF  (WD_OFF + 65536ul)      // 8*2*64
#define BD_OFF  (BC_OFF + 1024ul)

using f4 = __attribute__((ext_vector_type(4))) float;

// ---------------- K1: fuse head-mixture weights ----------------
__global__ __launch_bounds__(256) void fuse_weights(
        const float* __restrict__ aw, const float* __restrict__ Bw,
        const float* __restrict__ ab, const float* __restrict__ Bb,
        float* __restrict__ wc, float* __restrict__ wd,
        float* __restrict__ bc, float* __restrict__ bd) {
    int e = blockIdx.x * 256 + threadIdx.x;
    if (e < 131072) {
        int dd = e & 4095; int l = (e >> 12) & 1; int r = (e >> 13) & 7; int cd = e >> 16;
        float s = 0.f;
        #pragma unroll
        for (int h = 0; h < 4; ++h)
            s += aw[((cd*8 + r)*4 + h)*2 + l] * Bw[(h*2 + l)*4096 + dd];
        (cd ? wd : wc)[(r*2 + l)*4096 + dd] = s;
    } else {
        int e2 = e - 131072;
        if (e2 < 2048) {
            int d = e2 & 63; int l = (e2 >> 6) & 1; int r = (e2 >> 7) & 7; int cd = e2 >> 10;
            float s = 0.f;
            #pragma unroll
            for (int h = 0; h < 4; ++h)
                s += ab[((cd*8 + r)*4 + h)*2 + l] * Bb[(h*2 + l)*64 + d];
            (cd ? bd : bc)[(r*2 + l)*64 + d] = s;
        }
    }
}

// ---------------- K2: [B,D,N,T] -> [M,N,D] transpose ----------------
__global__ __launch_bounds__(256) void transpose_in(
        const float* __restrict__ x0, const float* __restrict__ x1,
        float* __restrict__ xs) {
    int bid = blockIdx.x;
    int n = bid % N_; int b = (bid / N_) % B_; int i = bid / (N_ * B_);
    const float* __restrict__ x = i ? x1 : x0;
    float* __restrict__ xo = xs + (size_t)i * MND_;
    __shared__ float tile[64][13];
    #pragma unroll
    for (int q = 0; q < 3; ++q) {
        int e = q * 256 + threadIdx.x;       // 0..767
        int d = e / 12, t = e % 12;
        tile[d][t] = x[(((size_t)b * D_ + d) * N_ + n) * T_ + t];
    }
    __syncthreads();
    #pragma unroll
    for (int q = 0; q < 3; ++q) {
        int e = q * 256 + threadIdx.x;
        int t = e >> 6, d = e & 63;
        xo[(((size_t)b * T_ + t) * N_ + n) * D_ + d] = tile[d][t];
    }
}

// ---------------- K3: aggregation GEMM: O[mm,d] = sum_n adj[n,mm] * X[n,d] ----------------
// block: 128 threads, tile 128(mm) x 64(d), micro-tile 8x8
__global__ __launch_bounds__(128) void aggregate(
        const float* __restrict__ graphs, const float* __restrict__ xs_in,
        float* __restrict__ agg) {
    const int cmb = blockIdx.z;          // t*2 + j
    const int t = cmb >> 1, j = cmb & 1;
    const int m = blockIdx.y;
    const int mm0 = blockIdx.x * 128;
    const float* __restrict__ adj = graphs + (size_t)t * N_ * N_;
    const float* __restrict__ X = xs_in + (size_t)j * MND_ + (size_t)m * N_ * D_;
    float* __restrict__ O = agg + (size_t)cmb * MND_ + (size_t)m * N_ * D_;

    __shared__ float As[32][132];
    __shared__ float Xs[32][68];
    const int tid = threadIdx.x;
    const int ty = tid >> 3;     // 0..15 -> mm group ty*8
    const int tx = tid & 7;      // 0..7  -> d group tx*8
    float acc[8][8] = {};

    for (int n0 = 0; n0 < N_; n0 += 32) {
        #pragma unroll
        for (int q = 0; q < 32; ++q) {
            int e = q * 128 + tid;
            int kk = e >> 7, mml = e & 127;
            int n = n0 + kk, mm = mm0 + mml;
            As[kk][mml] = (n < N_ && mm < N_) ? adj[(size_t)n * N_ + mm] : 0.f;
        }
        #pragma unroll
        for (int q = 0; q < 16; ++q) {
            int e = q * 128 + tid;
            int kk = e >> 6, dd = e & 63;
            int n = n0 + kk;
            Xs[kk][dd] = (n < N_) ? X[(size_t)n * D_ + dd] : 0.f;
        }
        __syncthreads();
        for (int kk = 0; kk < 32; ++kk) {
            f4 a0 = *(const f4*)&As[kk][ty * 8];
            f4 a1 = *(const f4*)&As[kk][ty * 8 + 4];
            f4 x0 = *(const f4*)&Xs[kk][tx * 8];
            f4 x1 = *(const f4*)&Xs[kk][tx * 8 + 4];
            #pragma unroll
            for (int im = 0; im < 8; ++im) {
                float av = (im < 4) ? a0[im] : a1[im - 4];
                #pragma unroll
                for (int id = 0; id < 4; ++id) {
                    acc[im][id]     = fmaf(av, x0[id], acc[im][id]);
                    acc[im][id + 4] = fmaf(av, x1[id], acc[im][id + 4]);
                }
            }
        }
        __syncthreads();
    }
    #pragma unroll
    for (int im = 0; im < 8; ++im) {
        int mm = mm0 + ty * 8 + im;
        if (mm < N_) {
            f4 v0, v1;
            #pragma unroll
            for (int id = 0; id < 4; ++id) { v0[id] = acc[im][id]; v1[id] = acc[im][id + 4]; }
            *(f4*)&O[(size_t)mm * D_ + tx * 8] = v0;
            *(f4*)&O[(size_t)mm * D_ + tx * 8 + 4] = v1;
        }
    }
}

// ---------------- K4: combine ----------------
__global__ __launch_bounds__(256) void combine(
        const float* __restrict__ agg,
        const float* __restrict__ wc, const float* __restrict__ wd,
        const float* __restrict__ bcv, const float* __restrict__ bdv,
        float* __restrict__ xs_out, int l) {
    const int i = blockIdx.y;
    const int row0 = blockIdx.x * 64;
    const int tid = threadIdx.x;
    const int ty = tid >> 4;            // row quad
    const int tx = tid & 15;            // d quad
    const int d0 = tx * 4;
    const size_t rbase = (size_t)(row0 + ty * 4) * 64;
    float hacc[4][4] = {};

    for (int t = 0; t < 2; ++t) {
        #pragma unroll
        for (int j = 0; j < 2; ++j) {
            const int rel = (t * 2 + i) * 2 + j;
            const float* __restrict__ Wc = wc + (size_t)(rel * 2 + l) * 4096 + d0;
            const float* __restrict__ Aj = agg + (size_t)(t * 2 + j) * MND_ + rbase;
            f4 cacc[4];
            {
                f4 bv = *(const f4*)&bcv[(rel * 2 + l) * 64 + d0];
                #pragma unroll
                for (int r = 0; r < 4; ++r) cacc[r] = bv;
            }
            for (int k4 = 0; k4 < 16; ++k4) {
                f4 a[4], w[4];
                #pragma unroll
                for (int r = 0; r < 4; ++r) a[r] = *(const f4*)&Aj[(size_t)r * 64 + k4 * 4];
                #pragma unroll
                for (int kk = 0; kk < 4; ++kk) w[kk] = *(const f4*)&Wc[(size_t)(k4 * 4 + kk) * 64];
                #pragma unroll
                for (int r = 0; r < 4; ++r)
                    #pragma unroll
                    for (int kk = 0; kk < 4; ++kk)
                        cacc[r] += a[r][kk] * w[kk];
            }
            #pragma unroll
            for (int r = 0; r < 4; ++r)
                #pragma unroll
                for (int dd = 0; dd < 4; ++dd)
                    hacc[r][dd] += fmaxf(cacc[r][dd], 0.f);

            if (j != i) {
                const float* __restrict__ Wd = wd + (size_t)(rel * 2 + l) * 4096 + d0;
                const float* __restrict__ Ai = agg + (size_t)(t * 2 + i) * MND_ + rbase;
                f4 dacc[4];
                f4 bv = *(const f4*)&bdv[(rel * 2 + l) * 64 + d0];
                #pragma unroll
                for (int r = 0; r < 4; ++r) dacc[r] = bv;
                for (int k4 = 0; k4 < 16; ++k4) {
                    f4 aj[4], ai[4], w[4];
                    #pragma unroll
                    for (int r = 0; r < 4; ++r) aj[r] = *(const f4*)&Aj[(size_t)r * 64 + k4 * 4];
                    #pragma unroll
                    for (int r = 0; r < 4; ++r) ai[r] = *(const f4*)&Ai[(size_t)r * 64 + k4 * 4];
                    #pragma unroll
                    for (int kk = 0; kk < 4; ++kk) w[kk] = *(const f4*)&Wd[(size_t)(k4 * 4 + kk) * 64];
                    #pragma unroll
                    for (int r = 0; r < 4; ++r) {
                        f4 df = aj[r] - ai[r];
                        #pragma unroll
                        for (int kk = 0; kk < 4; ++kk)
                            dacc[r] += df[kk] * w[kk];
                    }
                }
                #pragma unroll
                for (int r = 0; r < 4; ++r)
                    #pragma unroll
                    for (int dd = 0; dd < 4; ++dd)
                        hacc[r][dd] += tanhf(dacc[r][dd]);
            } else {
                f4 bv = *(const f4*)&bdv[(rel * 2 + l) * 64 + d0];
                float tb[4];
                #pragma unroll
                for (int dd = 0; dd < 4; ++dd) tb[dd] = tanhf(bv[dd]);
                #pragma unroll
                for (int r = 0; r < 4; ++r)
                    #pragma unroll
                    for (int dd = 0; dd < 4; ++dd)
                        hacc[r][dd] += tb[dd];
            }
        }
    }
    float* __restrict__ Ho = xs_out + (size_t)i * MND_ + rbase + d0;
    #pragma unroll
    for (int r = 0; r < 4; ++r) {
        f4 v;
        #pragma unroll
        for (int dd = 0; dd < 4; ++dd) v[dd] = hacc[r][dd];
        *(f4*)&Ho[(size_t)r * 64] = v;
    }
}

// ---------------- K5: summarize: weighted K-neighbor gather + transpose to [b,c,n,t] ----------------
// block: 192 threads (c = l*64+d). XCD-swizzled so the 126 blocks sharing one
// (i,b) 4.6MB source slice run contiguously on one XCD; tt-major gather loop
// keeps the instantaneous hot set to a few 384KB tt-slices; 48-row staging
// (37KB LDS) doubles occupancy to 4 blocks/CU.
__global__ __launch_bounds__(192) void summarize(
        const float* __restrict__ XS, const int* __restrict__ nbr,
        const float* __restrict__ nw, float* __restrict__ out) {
    // grid = 2016 = 8 XCD * 252.  work id: (i,b) outer, then t, then tile.
    int wg = (blockIdx.x & 7) * 252 + (blockIdx.x >> 3);
    int grp = wg / 126;            // 0..15 = i*8 + b
    int rem = wg % 126;            // t*63 + tile
    int i = grp >> 3, b = grp & 7;
    int t = rem / 63;
    int tile = rem % 63;
    int n0 = tile * 8;
    int tid = threadIdx.x;
    int l = tid >> 6, d = tid & 63;

    __shared__ int   nb_s[8][20];
    __shared__ float w_s[8][20];
    __shared__ float staged[48][193];   // 37.1 KB

    if (tid < 160) {
        int nn = tid / 20, k = tid % 20;
        int n = n0 + nn;
        nb_s[nn][k] = (n < N_) ? nbr[((size_t)t * N_ + n) * K_ + k] : 0;
        w_s[nn][k]  = (n < N_) ? nw[((size_t)t * N_ + n) * K_ + k] : 0.f;
    }
    __syncthreads();

    const float* __restrict__ Xbase = XS + ((size_t)l * 2 + i) * MND_ + (size_t)b * T_ * N_ * D_ + d;
    size_t obase = ((size_t)(i * 8 + b) * 384 + (size_t)t * 192) * 6000 + (size_t)n0 * 12;

    #pragma unroll
    for (int half = 0; half < 2; ++half) {
        const int nnb = half * 4;
        // compute, tt-major for temporal locality on the tt-slices
        for (int tt = 0; tt < 12; ++tt) {
            const float* __restrict__ Xm = Xbase + (size_t)tt * N_ * D_;
            #pragma unroll
            for (int nn2 = 0; nn2 < 4; ++nn2) {
                int nn = nnb + nn2;
                if (n0 + nn < N_) {
                    float acc = 0.f;
                    #pragma unroll
                    for (int k = 0; k < K_; ++k)
                        acc = fmaf(Xm[(size_t)nb_s[nn][k] * D_], w_s[nn][k], acc);
                    staged[nn2 * 12 + tt][tid] = acc;
                }
            }
        }
        __syncthreads();
        // flush: rows p (node-major within half) contiguous in output
        int plim = (N_ - n0 - nnb) * 12;
        if (plim > 48) plim = 48;
        if (plim > 0) {
            for (int it = 0; it < 48; ++it) {
                int e = it * 192 + tid;
                int c2 = e / 48, q = e % 48;
                if (q < plim)
                    out[obase + (size_t)c2 * 6000 + (size_t)nnb * 12 + q] = staged[q][c2];
            }
        }
        __syncthreads();
    }
}

extern "C" void kernel_launch(void* const* d_in, const int* in_sizes, int n_in,
                              void* d_out, int out_size, void* d_ws, size_t ws_size,
                              hipStream_t stream) {
    const float* x0     = (const float*)d_in[0];
    const float* x1     = (const float*)d_in[1];
    const float* graphs = (const float*)d_in[2];
    const int*   nbr    = (const int*)d_in[3];
    const float* nwt    = (const float*)d_in[4];
    const float* aw     = (const float*)d_in[5];
    const float* Bw     = (const float*)d_in[6];
    const float* ab     = (const float*)d_in[7];
    const float* Bb     = (const float*)d_in[8];
    float* out = (float*)d_out;
    float* ws  = (float*)d_ws;

    float* XS  = ws + XS_OFF;
    float* AGG = ws + AGG_OFF;
    float* WC  = ws + WC_OFF;
    float* WD  = ws + WD_OFF;
    float* BC  = ws + BC_OFF;
    float* BD  = ws + BD_OFF;

    fuse_weights<<<520, 256, 0, stream>>>(aw, Bw, ab, Bb, WC, WD, BC, BD);
    transpose_in<<<8000, 256, 0, stream>>>(x0, x1, XS);
    for (int l = 0; l < 2; ++l) {
        aggregate<<<dim3(4, 96, 4), 128, 0, stream>>>(graphs, XS + (size_t)l * 2 * MND_, AGG);
        combine<<<dim3(750, 2), 256, 0, stream>>>(AGG, WC, WD, BC, BD,
                                                  XS + (size_t)(l + 1) * 2 * MND_, l);
    }
    summarize<<<2016, 192, 0, stream>>>(XS, nbr, nwt, out);
}

// Round 3
// 1006.220 us; speedup vs baseline: 2.2339x; 2.2339x over previous
//
#include <hip/hip_runtime.h>
#include <math.h>

#define B_ 8
#define T_ 12
#define N_ 500
#define D_ 64
#define K_ 20
#define M_ (B_*T_)              // 96
#define MND_ 3072000            // M_*N_*D_
#define NROWS_ 48000            // M_*N_

// workspace layout (float offsets)
#define XS_OFF  0ul                     // 3 stages x 2 mix x MND_
#define AGG_OFF (6ul*MND_)              // 4 x MND_
#define WC_OFF  (AGG_OFF + 4ul*MND_)    // 8*2*4096
#define WD_OFF  (WC_OFF + 65536ul)
#define BC_OFF  (WD_OFF + 65536ul)      // 8*2*64
#define BD_OFF  (BC_OFF + 1024ul)

using f4 = __attribute__((ext_vector_type(4))) float;

// ---------------- K1: fuse head-mixture weights ----------------
__global__ __launch_bounds__(256) void fuse_weights(
        const float* __restrict__ aw, const float* __restrict__ Bw,
        const float* __restrict__ ab, const float* __restrict__ Bb,
        float* __restrict__ wc, float* __restrict__ wd,
        float* __restrict__ bc, float* __restrict__ bd) {
    int e = blockIdx.x * 256 + threadIdx.x;
    if (e < 131072) {
        int dd = e & 4095; int l = (e >> 12) & 1; int r = (e >> 13) & 7; int cd = e >> 16;
        float s = 0.f;
        #pragma unroll
        for (int h = 0; h < 4; ++h)
            s += aw[((cd*8 + r)*4 + h)*2 + l] * Bw[(h*2 + l)*4096 + dd];
        (cd ? wd : wc)[(r*2 + l)*4096 + dd] = s;
    } else {
        int e2 = e - 131072;
        if (e2 < 2048) {
            int d = e2 & 63; int l = (e2 >> 6) & 1; int r = (e2 >> 7) & 7; int cd = e2 >> 10;
            float s = 0.f;
            #pragma unroll
            for (int h = 0; h < 4; ++h)
                s += ab[((cd*8 + r)*4 + h)*2 + l] * Bb[(h*2 + l)*64 + d];
            (cd ? bd : bc)[(r*2 + l)*64 + d] = s;
        }
    }
}

// ---------------- K2: [B,D,N,T] -> [M,N,D] transpose ----------------
__global__ __launch_bounds__(256) void transpose_in(
        const float* __restrict__ x0, const float* __restrict__ x1,
        float* __restrict__ xs) {
    int bid = blockIdx.x;
    int n = bid % N_; int b = (bid / N_) % B_; int i = bid / (N_ * B_);
    const float* __restrict__ x = i ? x1 : x0;
    float* __restrict__ xo = xs + (size_t)i * MND_;
    __shared__ float tile[64][13];
    #pragma unroll
    for (int q = 0; q < 3; ++q) {
        int e = q * 256 + threadIdx.x;       // 0..767
        int d = e / 12, t = e % 12;
        tile[d][t] = x[(((size_t)b * D_ + d) * N_ + n) * T_ + t];
    }
    __syncthreads();
    #pragma unroll
    for (int q = 0; q < 3; ++q) {
        int e = q * 256 + threadIdx.x;
        int t = e >> 6, d = e & 63;
        xo[(((size_t)b * T_ + t) * N_ + n) * D_ + d] = tile[d][t];
    }
}

// ---------------- K3: aggregation GEMM: O[mm,d] = sum_n adj[n,mm] * X[n,d] ----------------
// block: 128 threads, tile 128(mm) x 64(d), micro-tile 8x8
__global__ __launch_bounds__(128) void aggregate(
        const float* __restrict__ graphs, const float* __restrict__ xs_in,
        float* __restrict__ agg) {
    const int cmb = blockIdx.z;          // t*2 + j
    const int t = cmb >> 1, j = cmb & 1;
    const int m = blockIdx.y;
    const int mm0 = blockIdx.x * 128;
    const float* __restrict__ adj = graphs + (size_t)t * N_ * N_;
    const float* __restrict__ X = xs_in + (size_t)j * MND_ + (size_t)m * N_ * D_;
    float* __restrict__ O = agg + (size_t)cmb * MND_ + (size_t)m * N_ * D_;

    __shared__ float As[32][132];
    __shared__ float Xs[32][68];
    const int tid = threadIdx.x;
    const int ty = tid >> 3;     // 0..15 -> mm group ty*8
    const int tx = tid & 7;      // 0..7  -> d group tx*8
    float acc[8][8] = {};

    for (int n0 = 0; n0 < N_; n0 += 32) {
        #pragma unroll
        for (int q = 0; q < 32; ++q) {
            int e = q * 128 + tid;
            int kk = e >> 7, mml = e & 127;
            int n = n0 + kk, mm = mm0 + mml;
            As[kk][mml] = (n < N_ && mm < N_) ? adj[(size_t)n * N_ + mm] : 0.f;
        }
        #pragma unroll
        for (int q = 0; q < 16; ++q) {
            int e = q * 128 + tid;
            int kk = e >> 6, dd = e & 63;
            int n = n0 + kk;
            Xs[kk][dd] = (n < N_) ? X[(size_t)n * D_ + dd] : 0.f;
        }
        __syncthreads();
        for (int kk = 0; kk < 32; ++kk) {
            f4 a0 = *(const f4*)&As[kk][ty * 8];
            f4 a1 = *(const f4*)&As[kk][ty * 8 + 4];
            f4 x0 = *(const f4*)&Xs[kk][tx * 8];
            f4 x1 = *(const f4*)&Xs[kk][tx * 8 + 4];
            #pragma unroll
            for (int im = 0; im < 8; ++im) {
                float av = (im < 4) ? a0[im] : a1[im - 4];
                #pragma unroll
                for (int id = 0; id < 4; ++id) {
                    acc[im][id]     = fmaf(av, x0[id], acc[im][id]);
                    acc[im][id + 4] = fmaf(av, x1[id], acc[im][id + 4]);
                }
            }
        }
        __syncthreads();
    }
    #pragma unroll
    for (int im = 0; im < 8; ++im) {
        int mm = mm0 + ty * 8 + im;
        if (mm < N_) {
            f4 v0, v1;
            #pragma unroll
            for (int id = 0; id < 4; ++id) { v0[id] = acc[im][id]; v1[id] = acc[im][id + 4]; }
            *(f4*)&O[(size_t)mm * D_ + tx * 8] = v0;
            *(f4*)&O[(size_t)mm * D_ + tx * 8 + 4] = v1;
        }
    }
}

// ---------------- K4: combine ----------------
__global__ __launch_bounds__(256) void combine(
        const float* __restrict__ agg,
        const float* __restrict__ wc, const float* __restrict__ wd,
        const float* __restrict__ bcv, const float* __restrict__ bdv,
        float* __restrict__ xs_out, int l) {
    const int i = blockIdx.y;
    const int row0 = blockIdx.x * 64;
    const int tid = threadIdx.x;
    const int ty = tid >> 4;            // row quad
    const int tx = tid & 15;            // d quad
    const int d0 = tx * 4;
    const size_t rbase = (size_t)(row0 + ty * 4) * 64;
    float hacc[4][4] = {};

    for (int t = 0; t < 2; ++t) {
        #pragma unroll
        for (int j = 0; j < 2; ++j) {
            const int rel = (t * 2 + i) * 2 + j;
            const float* __restrict__ Wc = wc + (size_t)(rel * 2 + l) * 4096 + d0;
            const float* __restrict__ Aj = agg + (size_t)(t * 2 + j) * MND_ + rbase;
            f4 cacc[4];
            {
                f4 bv = *(const f4*)&bcv[(rel * 2 + l) * 64 + d0];
                #pragma unroll
                for (int r = 0; r < 4; ++r) cacc[r] = bv;
            }
            for (int k4 = 0; k4 < 16; ++k4) {
                f4 a[4], w[4];
                #pragma unroll
                for (int r = 0; r < 4; ++r) a[r] = *(const f4*)&Aj[(size_t)r * 64 + k4 * 4];
                #pragma unroll
                for (int kk = 0; kk < 4; ++kk) w[kk] = *(const f4*)&Wc[(size_t)(k4 * 4 + kk) * 64];
                #pragma unroll
                for (int r = 0; r < 4; ++r)
                    #pragma unroll
                    for (int kk = 0; kk < 4; ++kk)
                        cacc[r] += a[r][kk] * w[kk];
            }
            #pragma unroll
            for (int r = 0; r < 4; ++r)
                #pragma unroll
                for (int dd = 0; dd < 4; ++dd)
                    hacc[r][dd] += fmaxf(cacc[r][dd], 0.f);

            if (j != i) {
                const float* __restrict__ Wd = wd + (size_t)(rel * 2 + l) * 4096 + d0;
                const float* __restrict__ Ai = agg + (size_t)(t * 2 + i) * MND_ + rbase;
                f4 dacc[4];
                f4 bv = *(const f4*)&bdv[(rel * 2 + l) * 64 + d0];
                #pragma unroll
                for (int r = 0; r < 4; ++r) dacc[r] = bv;
                for (int k4 = 0; k4 < 16; ++k4) {
                    f4 aj[4], ai[4], w[4];
                    #pragma unroll
                    for (int r = 0; r < 4; ++r) aj[r] = *(const f4*)&Aj[(size_t)r * 64 + k4 * 4];
                    #pragma unroll
                    for (int r = 0; r < 4; ++r) ai[r] = *(const f4*)&Ai[(size_t)r * 64 + k4 * 4];
                    #pragma unroll
                    for (int kk = 0; kk < 4; ++kk) w[kk] = *(const f4*)&Wd[(size_t)(k4 * 4 + kk) * 64];
                    #pragma unroll
                    for (int r = 0; r < 4; ++r) {
                        f4 df = aj[r] - ai[r];
                        #pragma unroll
                        for (int kk = 0; kk < 4; ++kk)
                            dacc[r] += df[kk] * w[kk];
                    }
                }
                #pragma unroll
                for (int r = 0; r < 4; ++r)
                    #pragma unroll
                    for (int dd = 0; dd < 4; ++dd)
                        hacc[r][dd] += tanhf(dacc[r][dd]);
            } else {
                f4 bv = *(const f4*)&bdv[(rel * 2 + l) * 64 + d0];
                float tb[4];
                #pragma unroll
                for (int dd = 0; dd < 4; ++dd) tb[dd] = tanhf(bv[dd]);
                #pragma unroll
                for (int r = 0; r < 4; ++r)
                    #pragma unroll
                    for (int dd = 0; dd < 4; ++dd)
                        hacc[r][dd] += tb[dd];
            }
        }
    }
    float* __restrict__ Ho = xs_out + (size_t)i * MND_ + rbase + d0;
    #pragma unroll
    for (int r = 0; r < 4; ++r) {
        f4 v;
        #pragma unroll
        for (int dd = 0; dd < 4; ++dd) v[dd] = hacc[r][dd];
        *(f4*)&Ho[(size_t)r * 64] = v;
    }
}

// ---------------- K5: summarize ----------------
// Round-1 gather loop (one accumulator, 20 coalesced loads per p, low VGPR)
// + XCD swizzle for L2 locality (proven: FETCH 1.09GB -> 164MB)
// + two 48-row staging passes (LDS 38.4KB -> 4 blocks/CU) for 2x MLP.
__global__ __launch_bounds__(192) void summarize(
        const float* __restrict__ XS, const int* __restrict__ nbr,
        const float* __restrict__ nw, float* __restrict__ out) {
    // grid = 2016 = 8 XCD * 252.  work id: (i,b) outer, then t, then tile.
    int wg = (blockIdx.x & 7) * 252 + (blockIdx.x >> 3);
    int grp = wg / 126;            // 0..15 = i*8 + b
    int rem = wg % 126;            // t*63 + tile
    int i = grp >> 3, b = grp & 7;
    int t = rem / 63;
    int tile = rem % 63;
    int n0 = tile * 8;
    int tid = threadIdx.x;
    int l = tid >> 6, d = tid & 63;

    __shared__ int   nb_s[8][20];
    __shared__ float w_s[8][20];
    __shared__ float staged[48][193];   // 37.1 KB

    if (tid < 160) {
        int nn = tid / 20, k = tid % 20;
        int n = n0 + nn;
        nb_s[nn][k] = (n < N_) ? nbr[((size_t)t * N_ + n) * K_ + k] : 0;
        w_s[nn][k]  = (n < N_) ? nw[((size_t)t * N_ + n) * K_ + k] : 0.f;
    }
    __syncthreads();

    const float* __restrict__ Xbase = XS + ((size_t)l * 2 + i) * MND_ + (size_t)b * T_ * N_ * D_ + d;
    size_t obase = ((size_t)(i * 8 + b) * 384 + (size_t)t * 192) * 6000 + (size_t)n0 * 12;

    #pragma unroll
    for (int half = 0; half < 2; ++half) {
        const int nnb = half * 4;
        // EXACT round-1 inner loop shape: p-major, tt innermost, one accumulator.
        for (int p = 0; p < 48; ++p) {
            int nn = nnb + p / 12, tt = p % 12;
            if (n0 + nn >= N_) break;
            const float* __restrict__ Xm = Xbase + (size_t)tt * N_ * D_;
            float acc = 0.f;
            #pragma unroll
            for (int k = 0; k < K_; ++k)
                acc = fmaf(Xm[(size_t)nb_s[nn][k] * D_], w_s[nn][k], acc);
            staged[p][tid] = acc;
        }
        __syncthreads();
        // flush: rows q (node-major within half) contiguous in output
        int plim = (N_ - n0 - nnb) * 12;
        if (plim > 48) plim = 48;
        if (plim > 0) {
            for (int it = 0; it < 48; ++it) {
                int e = it * 192 + tid;
                int c2 = e / 48, q = e % 48;
                if (q < plim)
                    out[obase + (size_t)c2 * 6000 + (size_t)nnb * 12 + q] = staged[q][c2];
            }
        }
        __syncthreads();
    }
}

extern "C" void kernel_launch(void* const* d_in, const int* in_sizes, int n_in,
                              void* d_out, int out_size, void* d_ws, size_t ws_size,
                              hipStream_t stream) {
    const float* x0     = (const float*)d_in[0];
    const float* x1     = (const float*)d_in[1];
    const float* graphs = (const float*)d_in[2];
    const int*   nbr    = (const int*)d_in[3];
    const float* nwt    = (const float*)d_in[4];
    const float* aw     = (const float*)d_in[5];
    const float* Bw     = (const float*)d_in[6];
    const float* ab     = (const float*)d_in[7];
    const float* Bb     = (const float*)d_in[8];
    float* out = (float*)d_out;
    float* ws  = (float*)d_ws;

    float* XS  = ws + XS_OFF;
    float* AGG = ws + AGG_OFF;
    float* WC  = ws + WC_OFF;
    float* WD  = ws + WD_OFF;
    float* BC  = ws + BC_OFF;
    float* BD  = ws + BD_OFF;

    fuse_weights<<<520, 256, 0, stream>>>(aw, Bw, ab, Bb, WC, WD, BC, BD);
    transpose_in<<<8000, 256, 0, stream>>>(x0, x1, XS);
    for (int l = 0; l < 2; ++l) {
        aggregate<<<dim3(4, 96, 4), 128, 0, stream>>>(graphs, XS + (size_t)l * 2 * MND_, AGG);
        combine<<<dim3(750, 2), 256, 0, stream>>>(AGG, WC, WD, BC, BD,
                                                  XS + (size_t)(l + 1) * 2 * MND_, l);
    }
    summarize<<<2016, 192, 0, stream>>>(XS, nbr, nwt, out);
}

// Round 4
// 831.631 us; speedup vs baseline: 2.7029x; 1.2099x over previous
//
#include <hip/hip_runtime.h>
#include <hip/hip_bf16.h>
#include <math.h>

#define B_ 8
#define T_ 12
#define N_ 500
#define D_ 64
#define K_ 20
#define M_ (B_*T_)              // 96
#define MND_ 3072000            // M_*N_*D_

// workspace layout (float offsets)
#define XS_OFF  0ul                     // 3 stages x 2 mix x MND_
#define AGG_OFF (6ul*MND_)              // 4 x MND_
#define WC_OFF  (AGG_OFF + 4ul*MND_)    // 8*2*4096
#define WD_OFF  (WC_OFF + 65536ul)
#define BC_OFF  (WD_OFF + 65536ul)      // 8*2*64
#define BD_OFF  (BC_OFF + 1024ul)
// bf16 hi/lo buffers (sized in float units; 2 ushorts per float unit)
#define AT_HI_OFF (BD_OFF + 1024ul)         // 2*512*512 ushort = 262144 f-units
#define AT_LO_OFF (AT_HI_OFF + 262144ul)
#define XT_HI_OFF (AT_LO_OFF + 262144ul)    // 2*96*64*512 ushort = 3145728 f-units
#define XT_LO_OFF (XT_HI_OFF + 3145728ul)
// end: 37,668,864 floats = 150.7 MB

using f4 = __attribute__((ext_vector_type(4))) float;
typedef __attribute__((ext_vector_type(8))) short bf16x8;
typedef __attribute__((ext_vector_type(4))) float f32x4;

__device__ inline void split_bf16(float v, ushort& h, ushort& l) {
    __hip_bfloat16 bh = __float2bfloat16(v);
    float fh = __bfloat162float(bh);
    __hip_bfloat16 bl = __float2bfloat16(v - fh);
    h = *reinterpret_cast<ushort*>(&bh);
    l = *reinterpret_cast<ushort*>(&bl);
}

// ---------------- K1: fuse head-mixture weights ----------------
__global__ __launch_bounds__(256) void fuse_weights(
        const float* __restrict__ aw, const float* __restrict__ Bw,
        const float* __restrict__ ab, const float* __restrict__ Bb,
        float* __restrict__ wc, float* __restrict__ wd,
        float* __restrict__ bc, float* __restrict__ bd) {
    int e = blockIdx.x * 256 + threadIdx.x;
    if (e < 131072) {
        int dd = e & 4095; int l = (e >> 12) & 1; int r = (e >> 13) & 7; int cd = e >> 16;
        float s = 0.f;
        #pragma unroll
        for (int h = 0; h < 4; ++h)
            s += aw[((cd*8 + r)*4 + h)*2 + l] * Bw[(h*2 + l)*4096 + dd];
        (cd ? wd : wc)[(r*2 + l)*4096 + dd] = s;
    } else {
        int e2 = e - 131072;
        if (e2 < 2048) {
            int d = e2 & 63; int l = (e2 >> 6) & 1; int r = (e2 >> 7) & 7; int cd = e2 >> 10;
            float s = 0.f;
            #pragma unroll
            for (int h = 0; h < 4; ++h)
                s += ab[((cd*8 + r)*4 + h)*2 + l] * Bb[(h*2 + l)*64 + d];
            (cd ? bd : bc)[(r*2 + l)*64 + d] = s;
        }
    }
}

// ---------------- K2: [B,D,N,T] -> [M,N,D] transpose ----------------
__global__ __launch_bounds__(256) void transpose_in(
        const float* __restrict__ x0, const float* __restrict__ x1,
        float* __restrict__ xs) {
    int bid = blockIdx.x;
    int n = bid % N_; int b = (bid / N_) % B_; int i = bid / (N_ * B_);
    const float* __restrict__ x = i ? x1 : x0;
    float* __restrict__ xo = xs + (size_t)i * MND_;
    __shared__ float tile[64][13];
    #pragma unroll
    for (int q = 0; q < 3; ++q) {
        int e = q * 256 + threadIdx.x;       // 0..767
        int d = e / 12, t = e % 12;
        tile[d][t] = x[(((size_t)b * D_ + d) * N_ + n) * T_ + t];
    }
    __syncthreads();
    #pragma unroll
    for (int q = 0; q < 3; ++q) {
        int e = q * 256 + threadIdx.x;
        int t = e >> 6, d = e & 63;
        xo[(((size_t)b * T_ + t) * N_ + n) * D_ + d] = tile[d][t];
    }
}

// ---------------- K3a: adjT bf16 hi/lo prep: AT[t][mm][n] = graphs[t][n][mm], padded 512x512 ----------------
__global__ __launch_bounds__(256) void adj_prep(
        const float* __restrict__ graphs,
        ushort* __restrict__ AT_hi, ushort* __restrict__ AT_lo) {
    int t = blockIdx.z;
    int n0 = blockIdx.x * 32, mm0 = blockIdx.y * 32;
    __shared__ float tile[32][33];
    int cc = threadIdx.x & 31, rr = threadIdx.x >> 5;   // 8 rows per iter
    #pragma unroll
    for (int it = 0; it < 4; ++it) {
        int n = n0 + it * 8 + rr, mm = mm0 + cc;
        tile[it * 8 + rr][cc] = (n < N_ && mm < N_)
            ? graphs[(size_t)t * 250000 + (size_t)n * 500 + mm] : 0.f;
    }
    __syncthreads();
    #pragma unroll
    for (int it = 0; it < 4; ++it) {
        int mml = it * 8 + rr, nl = cc;
        float v = tile[nl][mml];
        ushort h, l; split_bf16(v, h, l);
        size_t idx = (size_t)t * 262144 + (size_t)(mm0 + mml) * 512 + n0 + nl;
        AT_hi[idx] = h; AT_lo[idx] = l;
    }
}

// ---------------- K3b: X transpose-cast: XT[i][m][d][n(512)] hi/lo from xs[i][m][n][d] ----------------
__global__ __launch_bounds__(256) void xt_cast(
        const float* __restrict__ xs,
        ushort* __restrict__ XT_hi, ushort* __restrict__ XT_lo) {
    int i = blockIdx.z, m = blockIdx.y, c = blockIdx.x;  // c = n-chunk (0..7)
    int n0 = c * 64;
    __shared__ float tile[64][65];
    int d = threadIdx.x & 63, r4 = threadIdx.x >> 6;     // 4 n-rows per iter
    const float* __restrict__ src = xs + (size_t)i * MND_ + (size_t)m * 32000;
    #pragma unroll
    for (int it = 0; it < 16; ++it) {
        int nl = it * 4 + r4; int n = n0 + nl;
        tile[nl][d] = (n < N_) ? src[(size_t)n * 64 + d] : 0.f;
    }
    __syncthreads();
    size_t base = (size_t)(i * 96 + m) * 64 * 512 + n0;
    #pragma unroll
    for (int it = 0; it < 16; ++it) {
        int dl = it * 4 + r4; int nl = threadIdx.x & 63;
        float v = tile[nl][dl];
        ushort h, l; split_bf16(v, h, l);
        XT_hi[base + (size_t)dl * 512 + nl] = h;
        XT_lo[base + (size_t)dl * 512 + nl] = l;
    }
}

// ---------------- K3c: aggregation via MFMA, LDS-free ----------------
// O[mm,d] = sum_n adjT[mm,n] * X[m][n,d], per (cmb = t*2+j, m).
// A = AT[t] (512x512 bf16, k=n contiguous); B = XT[j][m] (64 d-rows x 512 n, k contiguous).
// Block = 1 wave, tile 64(mm) x 64(d): 4x4 16x16x32 fragments, 3-product hi/lo split.
__global__ __launch_bounds__(64) void aggregate_mfma(
        const ushort* __restrict__ AT_hi, const ushort* __restrict__ AT_lo,
        const ushort* __restrict__ XT_hi, const ushort* __restrict__ XT_lo,
        float* __restrict__ agg) {
    const int cmb = blockIdx.z;          // t*2 + j
    const int t = cmb >> 1, j = cmb & 1;
    const int m = blockIdx.y;
    const int mm0 = blockIdx.x * 64;
    const int lane = threadIdx.x;
    const int lr = lane & 15;
    const int lk = (lane >> 4) * 8;

    const ushort* __restrict__ A_h = AT_hi + (size_t)t * 262144 + (size_t)(mm0 + lr) * 512 + lk;
    const ushort* __restrict__ A_l = AT_lo + (size_t)t * 262144 + (size_t)(mm0 + lr) * 512 + lk;
    const ushort* __restrict__ B_h = XT_hi + ((size_t)(j * 96 + m) * 64 + lr) * 512 + lk;
    const ushort* __restrict__ B_l = XT_lo + ((size_t)(j * 96 + m) * 64 + lr) * 512 + lk;

    f32x4 acc[4][4] = {};

    for (int k0 = 0; k0 < 512; k0 += 32) {
        bf16x8 ah[4], al[4], bh[4], bl[4];
        #pragma unroll
        for (int f = 0; f < 4; ++f) {
            ah[f] = *(const bf16x8*)(A_h + (size_t)f * 8192 + k0);   // f*16 rows * 512
            al[f] = *(const bf16x8*)(A_l + (size_t)f * 8192 + k0);
            bh[f] = *(const bf16x8*)(B_h + (size_t)f * 8192 + k0);
            bl[f] = *(const bf16x8*)(B_l + (size_t)f * 8192 + k0);
        }
        #pragma unroll
        for (int fi = 0; fi < 4; ++fi)
            #pragma unroll
            for (int fj = 0; fj < 4; ++fj)
                acc[fi][fj] = __builtin_amdgcn_mfma_f32_16x16x32_bf16(ah[fi], bh[fj], acc[fi][fj], 0, 0, 0);
        #pragma unroll
        for (int fi = 0; fi < 4; ++fi)
            #pragma unroll
            for (int fj = 0; fj < 4; ++fj)
                acc[fi][fj] = __builtin_amdgcn_mfma_f32_16x16x32_bf16(ah[fi], bl[fj], acc[fi][fj], 0, 0, 0);
        #pragma unroll
        for (int fi = 0; fi < 4; ++fi)
            #pragma unroll
            for (int fj = 0; fj < 4; ++fj)
                acc[fi][fj] = __builtin_amdgcn_mfma_f32_16x16x32_bf16(al[fi], bh[fj], acc[fi][fj], 0, 0, 0);
    }

    float* __restrict__ O = agg + (size_t)cmb * MND_ + (size_t)m * 32000;
    #pragma unroll
    for (int fi = 0; fi < 4; ++fi) {
        #pragma unroll
        for (int reg = 0; reg < 4; ++reg) {
            int row = mm0 + fi * 16 + (lane >> 4) * 4 + reg;
            if (row < N_) {
                #pragma unroll
                for (int fj = 0; fj < 4; ++fj)
                    O[(size_t)row * 64 + fj * 16 + lr] = acc[fi][fj][reg];
            }
        }
    }
}

// ---------------- K4: combine ----------------
__global__ __launch_bounds__(256) void combine(
        const float* __restrict__ agg,
        const float* __restrict__ wc, const float* __restrict__ wd,
        const float* __restrict__ bcv, const float* __restrict__ bdv,
        float* __restrict__ xs_out, int l) {
    const int i = blockIdx.y;
    const int row0 = blockIdx.x * 64;
    const int tid = threadIdx.x;
    const int ty = tid >> 4;            // row quad
    const int tx = tid & 15;            // d quad
    const int d0 = tx * 4;
    const size_t rbase = (size_t)(row0 + ty * 4) * 64;
    float hacc[4][4] = {};

    for (int t = 0; t < 2; ++t) {
        #pragma unroll
        for (int j = 0; j < 2; ++j) {
            const int rel = (t * 2 + i) * 2 + j;
            const float* __restrict__ Wc = wc + (size_t)(rel * 2 + l) * 4096 + d0;
            const float* __restrict__ Aj = agg + (size_t)(t * 2 + j) * MND_ + rbase;
            f4 cacc[4];
            {
                f4 bv = *(const f4*)&bcv[(rel * 2 + l) * 64 + d0];
                #pragma unroll
                for (int r = 0; r < 4; ++r) cacc[r] = bv;
            }
            for (int k4 = 0; k4 < 16; ++k4) {
                f4 a[4], w[4];
                #pragma unroll
                for (int r = 0; r < 4; ++r) a[r] = *(const f4*)&Aj[(size_t)r * 64 + k4 * 4];
                #pragma unroll
                for (int kk = 0; kk < 4; ++kk) w[kk] = *(const f4*)&Wc[(size_t)(k4 * 4 + kk) * 64];
                #pragma unroll
                for (int r = 0; r < 4; ++r)
                    #pragma unroll
                    for (int kk = 0; kk < 4; ++kk)
                        cacc[r] += a[r][kk] * w[kk];
            }
            #pragma unroll
            for (int r = 0; r < 4; ++r)
                #pragma unroll
                for (int dd = 0; dd < 4; ++dd)
                    hacc[r][dd] += fmaxf(cacc[r][dd], 0.f);

            if (j != i) {
                const float* __restrict__ Wd = wd + (size_t)(rel * 2 + l) * 4096 + d0;
                const float* __restrict__ Ai = agg + (size_t)(t * 2 + i) * MND_ + rbase;
                f4 dacc[4];
                f4 bv = *(const f4*)&bdv[(rel * 2 + l) * 64 + d0];
                #pragma unroll
                for (int r = 0; r < 4; ++r) dacc[r] = bv;
                for (int k4 = 0; k4 < 16; ++k4) {
                    f4 aj[4], ai[4], w[4];
                    #pragma unroll
                    for (int r = 0; r < 4; ++r) aj[r] = *(const f4*)&Aj[(size_t)r * 64 + k4 * 4];
                    #pragma unroll
                    for (int r = 0; r < 4; ++r) ai[r] = *(const f4*)&Ai[(size_t)r * 64 + k4 * 4];
                    #pragma unroll
                    for (int kk = 0; kk < 4; ++kk) w[kk] = *(const f4*)&Wd[(size_t)(k4 * 4 + kk) * 64];
                    #pragma unroll
                    for (int r = 0; r < 4; ++r) {
                        f4 df = aj[r] - ai[r];
                        #pragma unroll
                        for (int kk = 0; kk < 4; ++kk)
                            dacc[r] += df[kk] * w[kk];
                    }
                }
                #pragma unroll
                for (int r = 0; r < 4; ++r)
                    #pragma unroll
                    for (int dd = 0; dd < 4; ++dd)
                        hacc[r][dd] += tanhf(dacc[r][dd]);
            } else {
                f4 bv = *(const f4*)&bdv[(rel * 2 + l) * 64 + d0];
                float tb[4];
                #pragma unroll
                for (int dd = 0; dd < 4; ++dd) tb[dd] = tanhf(bv[dd]);
                #pragma unroll
                for (int r = 0; r < 4; ++r)
                    #pragma unroll
                    for (int dd = 0; dd < 4; ++dd)
                        hacc[r][dd] += tb[dd];
            }
        }
    }
    float* __restrict__ Ho = xs_out + (size_t)i * MND_ + rbase + d0;
    #pragma unroll
    for (int r = 0; r < 4; ++r) {
        f4 v;
        #pragma unroll
        for (int dd = 0; dd < 4; ++dd) v[dd] = hacc[r][dd];
        *(f4*)&Ho[(size_t)r * 64] = v;
    }
}

// ---------------- K5: summarize (round-3 proven version) ----------------
__global__ __launch_bounds__(192) void summarize(
        const float* __restrict__ XS, const int* __restrict__ nbr,
        const float* __restrict__ nw, float* __restrict__ out) {
    // grid = 2016 = 8 XCD * 252.  work id: (i,b) outer, then t, then tile.
    int wg = (blockIdx.x & 7) * 252 + (blockIdx.x >> 3);
    int grp = wg / 126;            // 0..15 = i*8 + b
    int rem = wg % 126;            // t*63 + tile
    int i = grp >> 3, b = grp & 7;
    int t = rem / 63;
    int tile = rem % 63;
    int n0 = tile * 8;
    int tid = threadIdx.x;
    int l = tid >> 6, d = tid & 63;

    __shared__ int   nb_s[8][20];
    __shared__ float w_s[8][20];
    __shared__ float staged[48][193];   // 37.1 KB

    if (tid < 160) {
        int nn = tid / 20, k = tid % 20;
        int n = n0 + nn;
        nb_s[nn][k] = (n < N_) ? nbr[((size_t)t * N_ + n) * K_ + k] : 0;
        w_s[nn][k]  = (n < N_) ? nw[((size_t)t * N_ + n) * K_ + k] : 0.f;
    }
    __syncthreads();

    const float* __restrict__ Xbase = XS + ((size_t)l * 2 + i) * MND_ + (size_t)b * T_ * N_ * D_ + d;
    size_t obase = ((size_t)(i * 8 + b) * 384 + (size_t)t * 192) * 6000 + (size_t)n0 * 12;

    #pragma unroll
    for (int half = 0; half < 2; ++half) {
        const int nnb = half * 4;
        for (int p = 0; p < 48; ++p) {
            int nn = nnb + p / 12, tt = p % 12;
            if (n0 + nn >= N_) break;
            const float* __restrict__ Xm = Xbase + (size_t)tt * N_ * D_;
            float acc = 0.f;
            #pragma unroll
            for (int k = 0; k < K_; ++k)
                acc = fmaf(Xm[(size_t)nb_s[nn][k] * D_], w_s[nn][k], acc);
            staged[p][tid] = acc;
        }
        __syncthreads();
        int plim = (N_ - n0 - nnb) * 12;
        if (plim > 48) plim = 48;
        if (plim > 0) {
            for (int it = 0; it < 48; ++it) {
                int e = it * 192 + tid;
                int c2 = e / 48, q = e % 48;
                if (q < plim)
                    out[obase + (size_t)c2 * 6000 + (size_t)nnb * 12 + q] = staged[q][c2];
            }
        }
        __syncthreads();
    }
}

extern "C" void kernel_launch(void* const* d_in, const int* in_sizes, int n_in,
                              void* d_out, int out_size, void* d_ws, size_t ws_size,
                              hipStream_t stream) {
    const float* x0     = (const float*)d_in[0];
    const float* x1     = (const float*)d_in[1];
    const float* graphs = (const float*)d_in[2];
    const int*   nbr    = (const int*)d_in[3];
    const float* nwt    = (const float*)d_in[4];
    const float* aw     = (const float*)d_in[5];
    const float* Bw     = (const float*)d_in[6];
    const float* ab     = (const float*)d_in[7];
    const float* Bb     = (const float*)d_in[8];
    float* out = (float*)d_out;
    float* ws  = (float*)d_ws;

    float* XS  = ws + XS_OFF;
    float* AGG = ws + AGG_OFF;
    float* WC  = ws + WC_OFF;
    float* WD  = ws + WD_OFF;
    float* BC  = ws + BC_OFF;
    float* BD  = ws + BD_OFF;
    ushort* ATh = (ushort*)(ws + AT_HI_OFF);
    ushort* ATl = (ushort*)(ws + AT_LO_OFF);
    ushort* XTh = (ushort*)(ws + XT_HI_OFF);
    ushort* XTl = (ushort*)(ws + XT_LO_OFF);

    fuse_weights<<<520, 256, 0, stream>>>(aw, Bw, ab, Bb, WC, WD, BC, BD);
    transpose_in<<<8000, 256, 0, stream>>>(x0, x1, XS);
    adj_prep<<<dim3(16, 16, 2), 256, 0, stream>>>(graphs, ATh, ATl);
    for (int l = 0; l < 2; ++l) {
        xt_cast<<<dim3(8, 96, 2), 256, 0, stream>>>(XS + (size_t)l * 2 * MND_, XTh, XTl);
        aggregate_mfma<<<dim3(8, 96, 4), 64, 0, stream>>>(ATh, ATl, XTh, XTl, AGG);
        combine<<<dim3(750, 2), 256, 0, stream>>>(AGG, WC, WD, BC, BD,
                                                  XS + (size_t)(l + 1) * 2 * MND_, l);
    }
    summarize<<<2016, 192, 0, stream>>>(XS, nbr, nwt, out);
}